// Round 5
// baseline (2354.043 us; speedup 1.0000x reference)
//
#include <hip/hip_runtime.h>
#include <hip/hip_cooperative_groups.h>
#include <cstddef>

namespace cg = cooperative_groups;

#define DIM 256
#define NSLOT 8
#define BATCH 64
#define NTOK 4096
#define SEGB 16                 /* attn blocks per batch */
#define NPART SEGB              /* U/l partials per batch */
#define ITERS 3
#define EPS 1e-5f

typedef short bf16x8 __attribute__((ext_vector_type(8)));
typedef short bf16x4 __attribute__((ext_vector_type(4)));
typedef float f32x4  __attribute__((ext_vector_type(4)));

static __device__ __forceinline__ short f2bf(float f) {
    union { float f; unsigned u; } v; v.f = f;
    unsigned r = v.u + 0x7fffu + ((v.u >> 16) & 1u);   // RNE
    return (short)(r >> 16);
}

// ---------------- workspace layout (float offsets) ----------------
enum : size_t {
    OFF_M     = 0,                               // [256][256]  (Wq^T Wk) * d^-0.5
    OFF_WIHT  = OFF_M    + 256 * 256,            // [256][768]
    OFF_WHHT  = OFF_WIHT + 256 * 768,            // [256][768]
    OFF_WVT   = OFF_WHHT + 256 * 768,            // [256][256]
    OFF_W1T   = OFF_WVT  + 256 * 256,            // [256][256]
    OFF_W2T   = OFF_W1T  + 256 * 256,            // [256][256]
    OFF_SLOTS = OFF_W2T  + 256 * 256,            // [512][256]
    OFF_SNEW  = OFF_SLOTS + BATCH * NSLOT * 256, // [512][256]
    OFF_QT    = OFF_SNEW  + BATCH * NSLOT * 256, // [512][256]
    OFF_H     = OFF_QT    + BATCH * NSLOT * 256, // [512][256]
    OFF_UPD   = OFF_H     + BATCH * NSLOT * 256, // [512][256]
    OFF_UPART = OFF_UPD   + BATCH * NSLOT * 256, // [64][NPART][8][256]
    OFF_LPART = OFF_UPART + (size_t)BATCH * NPART * NSLOT * 256, // [64][NPART][16]
    OFF_XLN   = OFF_LPART + BATCH * NPART * 16,  // bf16 LN(x) token-major [64][4096][256]
    OFF_GH    = OFF_XLN   + (size_t)BATCH * NTOK * 128, // [512][768]
    OFF_GI    = OFF_GH    + 512 * 768,                  // [512][768]
    WS_FLOATS = OFF_GI    + 512 * 768
};

// ---------------- shared-memory union (39424 B) ----------------
union MegaShared {
    struct {
        short qhi[8 * 264];
        short xT[256 * 64];
        short Etmp[16 * 72];
        float lsum[4][8];
    } a;
    struct {
        float At[8][256];
        float lrow[8];
    } g;
};

// ---------------- prologue kernels ----------------
__global__ __launch_bounds__(256) void k_transpose(const float* __restrict__ w_ih,
                                                   const float* __restrict__ w_hh,
                                                   const float* __restrict__ wv,
                                                   const float* __restrict__ w1,
                                                   const float* __restrict__ w2,
                                                   float* __restrict__ ws) {
    int z = blockIdx.z;
    const float* src;
    float* dst;
    int R;
    if (z == 0)      { src = w_ih; dst = ws + OFF_WIHT; R = 768; }
    else if (z == 1) { src = w_hh; dst = ws + OFF_WHHT; R = 768; }
    else if (z == 2) { src = wv;   dst = ws + OFF_WVT;  R = 256; }
    else if (z == 3) { src = w1;   dst = ws + OFF_W1T;  R = 256; }
    else             { src = w2;   dst = ws + OFF_W2T;  R = 256; }
    if ((int)blockIdx.x * 32 >= R) return;
    __shared__ float tile[32][33];
    int lx = threadIdx.x & 31, ly = threadIdx.x >> 5;
    int r0 = blockIdx.x * 32, c0 = blockIdx.y * 32;
#pragma unroll
    for (int p = 0; p < 4; ++p)
        tile[ly + p * 8][lx] = src[(size_t)(r0 + ly + p * 8) * 256 + c0 + lx];
    __syncthreads();
#pragma unroll
    for (int p = 0; p < 4; ++p)
        dst[(size_t)(c0 + ly + p * 8) * R + r0 + lx] = tile[lx][ly + p * 8];
}

__global__ __launch_bounds__(256) void k_m(const float* __restrict__ wq,
                                           const float* __restrict__ wk,
                                           float* __restrict__ ws) {
    int d = blockIdx.x, t = threadIdx.x;
    float acc = 0.f;
    for (int e = 0; e < 256; ++e)
        acc += wq[e * 256 + d] * wk[e * 256 + t];
    ws[OFF_M + d * 256 + t] = acc * 0.0625f; // 256^-0.5
}

__global__ __launch_bounds__(256) void k_init(const float* __restrict__ mu,
                                              const float* __restrict__ logsig,
                                              const float* __restrict__ noise,
                                              float* __restrict__ ws) {
    int i = blockIdx.x * 256 + threadIdx.x;
    int d = i & 255;
    ws[OFF_SLOTS + i] = mu[d] + noise[i] * __expf(logsig[d]);
}

__global__ __launch_bounds__(256) void k_qt(float* __restrict__ ws,
                                            const float* __restrict__ g_sl,
                                            const float* __restrict__ be_sl) {
    __shared__ float ln[2048];
    int chunk = blockIdx.x, b = blockIdx.y;
    int t = threadIdx.x, wave = t >> 6, lane = t & 63;
    const float* slots = ws + OFF_SLOTS + b * 2048;
    float4 gf = ((const float4*)g_sl)[lane];
    float4 bf = ((const float4*)be_sl)[lane];
#pragma unroll
    for (int rr = 0; rr < 2; ++rr) {
        int r = wave + rr * 4;
        float4 v = ((const float4*)(slots + r * 256))[lane];
        float s1 = v.x + v.y + v.z + v.w;
        float s2 = v.x * v.x + v.y * v.y + v.z * v.z + v.w * v.w;
#pragma unroll
        for (int m = 1; m < 64; m <<= 1) { s1 += __shfl_xor(s1, m); s2 += __shfl_xor(s2, m); }
        float mu = s1 * (1.f / 256.f);
        float rstd = rsqrtf(s2 * (1.f / 256.f) - mu * mu + EPS);
        float4 o;
        o.x = (v.x - mu) * rstd * gf.x + bf.x;
        o.y = (v.y - mu) * rstd * gf.y + bf.y;
        o.z = (v.z - mu) * rstd * gf.z + bf.z;
        o.w = (v.w - mu) * rstd * gf.w + bf.w;
        *((float4*)&ln[r * 256 + lane * 4]) = o;
    }
    __syncthreads();
    const float* M = ws + OFF_M;
    int k0 = t >> 6;
    int e = chunk * 64 + (t & 63);
    float a0 = 0.f, a1 = 0.f;
    for (int d = 0; d < 256; ++d) {
        float m = M[d * 256 + e];
        a0 += ln[k0 * 256 + d] * m;
        a1 += ln[(k0 + 4) * 256 + d] * m;
    }
    float* qt = ws + OFF_QT + b * 2048;
    qt[k0 * 256 + e] = a0;
    qt[(k0 + 4) * 256 + e] = a1;
}

// ---------------- attention phase (device fn; R3-proven math, afn removed) ----------------
__device__ __forceinline__ void attn_phase(bool p1, int unit, int t,
                                           const float* __restrict__ x,
                                           const float* __restrict__ g_in,
                                           const float* __restrict__ be_in,
                                           float* __restrict__ ws,
                                           MegaShared& sh) {
    int seg = unit & 15, b = unit >> 4;
    int w = t >> 6, lane = t & 63;
    int q = lane >> 4, s16 = lane & 15;

    const float* qtg = ws + OFF_QT + b * 2048;
    for (int idx = t; idx < 8 * 264; idx += 256) {
        int s = idx / 264;
        int d = idx - s * 264;
        sh.a.qhi[idx] = (d < 256) ? f2bf(qtg[s * 256 + d]) : (short)0;
    }
    __syncthreads();

    bf16x8 qf[8];
#pragma unroll
    for (int i = 0; i < 8; ++i) {
        if (s16 < 8) qf[i] = *(const bf16x8*)&sh.a.qhi[s16 * 264 + i * 32 + q * 8];
        else         qf[i] = (bf16x8){0, 0, 0, 0, 0, 0, 0, 0};
    }

    f32x4 U[4];
#pragma unroll
    for (int c = 0; c < 4; ++c) U[c] = (f32x4){0.f, 0.f, 0.f, 0.f};
    float lacc = 0.f;

    short* xln = (short*)(ws + OFF_XLN);
    int mytok = seg * 256 + w * 16 + s16;
    int g0 = ((w * 16 + s16) >> 3);
    int t7 = s16 & 7;

    bf16x8 af[8];
    if (!p1) {
        const short* xr = xln + ((size_t)b * NTOK + mytok) * 256 + q * 8;
#pragma unroll
        for (int i = 0; i < 8; ++i) af[i] = *(const bf16x8*)&xr[i * 32];
    }

    for (int tt = 0; tt < 4; ++tt) {
        int tok = mytok + tt * 64;
        if (p1) {
            const float4* xp = (const float4*)(x + ((size_t)b * NTOK + tok) * 256 + q * 8);
            float s1 = 0.f, s2 = 0.f;
#pragma unroll
            for (int i = 0; i < 8; ++i) {          // stats pass (values re-read below via L1)
                float4 a = xp[8 * i], bv = xp[8 * i + 1];
                s1 += a.x + a.y + a.z + a.w + bv.x + bv.y + bv.z + bv.w;
                s2 += a.x * a.x + a.y * a.y + a.z * a.z + a.w * a.w
                    + bv.x * bv.x + bv.y * bv.y + bv.z * bv.z + bv.w * bv.w;
            }
            s1 += __shfl_xor(s1, 16); s2 += __shfl_xor(s2, 16);
            s1 += __shfl_xor(s1, 32); s2 += __shfl_xor(s2, 32);
            float mu = s1 * (1.f / 256.f);
            float rstd = rsqrtf(s2 * (1.f / 256.f) - mu * mu + EPS);
            short* xrow = xln + ((size_t)b * NTOK + tok) * 256;
#pragma unroll
            for (int i = 0; i < 8; ++i) {
                float4 a = xp[8 * i], bv = xp[8 * i + 1];
                int dbase = i * 32 + q * 8;
                float4 gA = *(const float4*)&g_in[dbase];
                float4 gB = *(const float4*)&g_in[dbase + 4];
                float4 bA = *(const float4*)&be_in[dbase];
                float4 bB = *(const float4*)&be_in[dbase + 4];
                bf16x8 f;
                f[0] = f2bf((a.x - mu) * rstd * gA.x + bA.x);
                f[1] = f2bf((a.y - mu) * rstd * gA.y + bA.y);
                f[2] = f2bf((a.z - mu) * rstd * gA.z + bA.z);
                f[3] = f2bf((a.w - mu) * rstd * gA.w + bA.w);
                f[4] = f2bf((bv.x - mu) * rstd * gB.x + bB.x);
                f[5] = f2bf((bv.y - mu) * rstd * gB.y + bB.y);
                f[6] = f2bf((bv.z - mu) * rstd * gB.z + bB.z);
                f[7] = f2bf((bv.w - mu) * rstd * gB.w + bB.w);
                af[i] = f;
                *(bf16x8*)&xrow[dbase] = f;
            }
        }

        // ---- QK^T: two independent MFMA chains ----
        f32x4 Lc0 = (f32x4){0.f, 0.f, 0.f, 0.f};
        f32x4 Lc1 = (f32x4){0.f, 0.f, 0.f, 0.f};
#pragma unroll
        for (int i = 0; i < 4; ++i) {
            Lc0 = __builtin_amdgcn_mfma_f32_16x16x32_bf16(af[i],     qf[i],     Lc0, 0, 0, 0);
            Lc1 = __builtin_amdgcn_mfma_f32_16x16x32_bf16(af[i + 4], qf[i + 4], Lc1, 0, 0, 0);
        }

        bf16x4 e2;
#pragma unroll
        for (int r = 0; r < 4; ++r) {
            float E = __expf(fminf(Lc0[r] + Lc1[r], 30.f));
            lacc += E;
            e2[r] = f2bf(E);
        }

        __syncthreads();   // (A) previous tile's xT/Etmp reads complete

#pragma unroll
        for (int i = 0; i < 8; ++i) {
            int Ki = (4 * i + q) & 7;
            int dbase = i * 32 + q * 8;
            bf16x8 f = af[i];
#pragma unroll
            for (int e = 0; e < 8; ++e) {
                int gp = (g0 ^ e ^ Ki) & 7;
                sh.a.xT[((dbase + e) << 6) + (gp << 3) + t7] = f[e];
            }
        }
        *(bf16x4*)&sh.a.Etmp[s16 * 72 + w * 16 + q * 4] = e2;

        __syncthreads();   // (B) xT + Etmp ready; af now dead

        // ---- prefetch next tile's A-frags INTO af (dead after scatter) ----
        if (!p1 && tt < 3) {
            const short* xr = xln + ((size_t)b * NTOK + tok + 64) * 256 + q * 8;
#pragma unroll
            for (int i = 0; i < 8; ++i) af[i] = *(const bf16x8*)&xr[i * 32];
        }

        bf16x8 ea0 = *(const bf16x8*)&sh.a.Etmp[s16 * 72 + q * 8];
        bf16x8 ea1 = *(const bf16x8*)&sh.a.Etmp[s16 * 72 + 32 + q * 8];
#pragma unroll
        for (int c = 0; c < 4; ++c) {
            int d = (4 * w + c) * 16 + s16;
            int swz = (d ^ (d >> 3)) & 7;
            const short* row = &sh.a.xT[d << 6];
            bf16x8 b0 = *(const bf16x8*)&row[((q ^ swz) & 7) << 3];
            bf16x8 b1 = *(const bf16x8*)&row[(((4 + q) ^ swz) & 7) << 3];
            U[c] = __builtin_amdgcn_mfma_f32_16x16x32_bf16(ea0, b0, U[c], 0, 0, 0);
            U[c] = __builtin_amdgcn_mfma_f32_16x16x32_bf16(ea1, b1, U[c], 0, 0, 0);
        }
    }

    lacc += __shfl_xor(lacc, 16); lacc += __shfl_xor(lacc, 32);
    __syncthreads();
    if (q == 0 && s16 < 8) sh.a.lsum[w][s16] = lacc;
    __syncthreads();
    float* lpart = ws + OFF_LPART + (size_t)(b * NPART + seg) * 16;
    if (t < 8) lpart[t] = sh.a.lsum[0][t] + sh.a.lsum[1][t] + sh.a.lsum[2][t] + sh.a.lsum[3][t];
    float* up = ws + OFF_UPART + (size_t)(b * NPART + seg) * NSLOT * 256;
#pragma unroll
    for (int c = 0; c < 4; ++c) {
        int d = (4 * w + c) * 16 + s16;
#pragma unroll
        for (int r = 0; r < 4; ++r) {
            int slot = q * 4 + r;
            if (slot < 8) up[slot * 256 + d] = U[c][r];
        }
    }
}

// ---------------- tiled GEMM phase: out[8r x 64c] = A[8 x 256] @ W[256 x C] ----------------
enum { GF_LN = 1, GF_RELU = 2, GF_BIAS = 4, GF_ADD = 8, GF_OUT = 16 };

template <int C, int FLAGS>
__device__ __forceinline__ void gemm_full(MegaShared& sh, int t,
        const float* __restrict__ A, const float* __restrict__ W,
        float* __restrict__ O, int rtile, int ctile,
        const float* __restrict__ g, const float* __restrict__ be,
        const float* __restrict__ bias, const float* __restrict__ addsrc,
        float* __restrict__ dout) {
    const int r0 = rtile * 8, c0 = ctile * 64;
    {
        int r = t >> 5, c8 = (t & 31) * 8;
        const float* src = A + (size_t)(r0 + r) * 256 + c8;
        *(float4*)&sh.g.At[r][c8]     = *(const float4*)src;
        *(float4*)&sh.g.At[r][c8 + 4] = *(const float4*)(src + 4);
    }
    __syncthreads();
    if (FLAGS & GF_LN) {
        int wv = t >> 6, lane = t & 63;
        float4 gf = ((const float4*)g)[lane];
        float4 bf = ((const float4*)be)[lane];
#pragma unroll
        for (int rr = 0; rr < 2; ++rr) {
            int row = wv + rr * 4;
            float4 v = *(float4*)&sh.g.At[row][lane * 4];
            float s1 = v.x + v.y + v.z + v.w;
            float s2 = v.x * v.x + v.y * v.y + v.z * v.z + v.w * v.w;
#pragma unroll
            for (int m = 1; m < 64; m <<= 1) { s1 += __shfl_xor(s1, m); s2 += __shfl_xor(s2, m); }
            float mu = s1 * (1.f / 256.f);
            float rstd = rsqrtf(s2 * (1.f / 256.f) - mu * mu + EPS);
            float4 o;
            o.x = (v.x - mu) * rstd * gf.x + bf.x;
            o.y = (v.y - mu) * rstd * gf.y + bf.y;
            o.z = (v.z - mu) * rstd * gf.z + bf.z;
            o.w = (v.w - mu) * rstd * gf.w + bf.w;
            *(float4*)&sh.g.At[row][lane * 4] = o;
        }
        __syncthreads();
    }
    int ct = t & 63, rt = t >> 6;
    int c = c0 + ct;
    float acc0 = 0.f, acc1 = 0.f;
#pragma unroll 4
    for (int dd = 0; dd < 256; dd += 4) {
        float w0 = W[(size_t)(dd + 0) * C + c];
        float w1 = W[(size_t)(dd + 1) * C + c];
        float w2 = W[(size_t)(dd + 2) * C + c];
        float w3 = W[(size_t)(dd + 3) * C + c];
        float4 a0 = *(const float4*)&sh.g.At[rt * 2 + 0][dd];
        float4 a1 = *(const float4*)&sh.g.At[rt * 2 + 1][dd];
        acc0 += a0.x * w0 + a0.y * w1 + a0.z * w2 + a0.w * w3;
        acc1 += a1.x * w0 + a1.y * w1 + a1.z * w2 + a1.w * w3;
    }
    float bb = (FLAGS & GF_BIAS) ? bias[c] : 0.f;
    int r = r0 + rt * 2;
    float v0 = acc0 + bb, v1 = acc1 + bb;
    if (FLAGS & GF_RELU) { v0 = fmaxf(v0, 0.f); v1 = fmaxf(v1, 0.f); }
    if (FLAGS & GF_ADD)  { v0 += addsrc[(size_t)r * 256 + c]; v1 += addsrc[(size_t)(r + 1) * 256 + c]; }
    O[(size_t)r * C + c] = v0;
    O[(size_t)(r + 1) * C + c] = v1;
    if (FLAGS & GF_OUT) {
        if (dout) { dout[(size_t)r * 256 + c] = v0; dout[(size_t)(r + 1) * 256 + c] = v1; }
    }
}

// ---------------- upd GEMM with in-block uc build ----------------
__device__ __forceinline__ void phase_upd(MegaShared& sh, int t, float* __restrict__ ws,
                                          int rtile, int ctile) {
    const int r0 = rtile * 8, c0 = ctile * 64;
    if (t < 8) {
        int rr = r0 + t, b = rr >> 3, s = rr & 7;
        float l = 0.f;
#pragma unroll
        for (int g = 0; g < NPART; ++g)
            l += ws[OFF_LPART + (size_t)(b * NPART + g) * 16 + s];
        sh.g.lrow[t] = l;
    }
    {
        int r = t >> 5, c8 = (t & 31) * 8;
        int rr = r0 + r, b = rr >> 3, s = rr & 7;
        const float* base = ws + OFF_UPART + (size_t)b * (NPART * 2048) + (size_t)s * 256 + c8;
        float a0 = 0.f, a1 = 0.f, a2 = 0.f, a3 = 0.f, a4 = 0.f, a5 = 0.f, a6 = 0.f, a7 = 0.f;
#pragma unroll
        for (int g = 0; g < NPART; ++g) {
            const float4* p = (const float4*)(base + (size_t)g * 2048);
            float4 u0 = p[0], u1 = p[1];
            a0 += u0.x; a1 += u0.y; a2 += u0.z; a3 += u0.w;
            a4 += u1.x; a5 += u1.y; a6 += u1.z; a7 += u1.w;
        }
        __syncthreads();   // lrow ready
        float inv = 1.f / sh.g.lrow[r];
        float4 o0 = {a0 * inv, a1 * inv, a2 * inv, a3 * inv};
        float4 o1 = {a4 * inv, a5 * inv, a6 * inv, a7 * inv};
        *(float4*)&sh.g.At[r][c8]     = o0;
        *(float4*)&sh.g.At[r][c8 + 4] = o1;
    }
    __syncthreads();
    int ct = t & 63, rt = t >> 6;
    int c = c0 + ct;
    const float* W = ws + OFF_WVT;
    float acc0 = 0.f, acc1 = 0.f;
#pragma unroll 4
    for (int dd = 0; dd < 256; dd += 4) {
        float w0 = W[(size_t)(dd + 0) * 256 + c];
        float w1 = W[(size_t)(dd + 1) * 256 + c];
        float w2 = W[(size_t)(dd + 2) * 256 + c];
        float w3 = W[(size_t)(dd + 3) * 256 + c];
        float4 a0 = *(const float4*)&sh.g.At[rt * 2 + 0][dd];
        float4 a1 = *(const float4*)&sh.g.At[rt * 2 + 1][dd];
        acc0 += a0.x * w0 + a0.y * w1 + a0.z * w2 + a0.w * w3;
        acc1 += a1.x * w0 + a1.y * w1 + a1.z * w2 + a1.w * w3;
    }
    float* O = ws + OFF_UPD;
    int r = r0 + rt * 2;
    O[(size_t)r * 256 + c] = acc0;
    O[(size_t)(r + 1) * 256 + c] = acc1;
}

// ---------------- GRU elementwise combine ----------------
__device__ __forceinline__ void phase_gru(int u, int t, float* __restrict__ ws,
                                          const float* __restrict__ b_ih,
                                          const float* __restrict__ b_hh) {
    int idx = u * 256 + t;
    int c = idx & 255;
    size_t r = (size_t)(idx >> 8);
    const float* GI = ws + OFF_GI;
    const float* GH = ws + OFF_GH;
    float gir = GI[r * 768 + c], giz = GI[r * 768 + 256 + c], gin2 = GI[r * 768 + 512 + c];
    float ghr = GH[r * 768 + c], ghz = GH[r * 768 + 256 + c], ghn = GH[r * 768 + 512 + c];
    float hv = ws[OFF_SLOTS + idx];
    float rg = 1.f / (1.f + __expf(-(gir + b_ih[c] + ghr + b_hh[c])));
    float zg = 1.f / (1.f + __expf(-(giz + b_ih[256 + c] + ghz + b_hh[256 + c])));
    float ng = tanhf(gin2 + b_ih[512 + c] + rg * (ghn + b_hh[512 + c]));
    ws[OFF_SNEW + idx] = (1.f - zg) * ng + zg * hv;
}

// ---------------- cooperative mega-kernel: grid-stride phases, any grid in {256,512,1024} ----------------
__global__ __launch_bounds__(256, 4) void k_mega(
        const float* __restrict__ x,
        const float* __restrict__ g_in, const float* __restrict__ be_in,
        const float* __restrict__ b_ih, const float* __restrict__ b_hh,
        const float* __restrict__ g_ff, const float* __restrict__ be_ff,
        const float* __restrict__ b1p, const float* __restrict__ b2p,
        const float* __restrict__ g_sl, const float* __restrict__ be_sl,
        float* __restrict__ ws, float* __restrict__ dout) {
    cg::grid_group gg = cg::this_grid();
    __shared__ MegaShared sh;
    int t = threadIdx.x;
    int G = gridDim.x;

    for (int it = 0; it < ITERS; ++it) {
        bool p1 = (it == 0), last = (it == ITERS - 1);
        for (int u = blockIdx.x; u < 1024; u += G) {
            attn_phase(p1, u, t, x, g_in, be_in, ws, sh);
            __syncthreads();
        }
        gg.sync();
        // Phase B: upd (tiles 0-255) || gh = slots_prev @ WhhT (tiles 256-1023)
        for (int u = blockIdx.x; u < 1024; u += G) {
            if (u < 256) phase_upd(sh, t, ws, u >> 2, u & 3);
            else {
                int k = u - 256;
                gemm_full<768, 0>(sh, t, ws + OFF_SLOTS, ws + OFF_WHHT, ws + OFF_GH,
                                  k / 12, k % 12, nullptr, nullptr, nullptr, nullptr, nullptr);
            }
            __syncthreads();
        }
        gg.sync();
        // Phase C: gi = upd @ WihT
        for (int u = blockIdx.x; u < 768; u += G) {
            gemm_full<768, 0>(sh, t, ws + OFF_UPD, ws + OFF_WIHT, ws + OFF_GI,
                              u / 12, u % 12, nullptr, nullptr, nullptr, nullptr, nullptr);
            __syncthreads();
        }
        gg.sync();
        // Phase D: GRU combine -> snew
        for (int u = blockIdx.x; u < 512; u += G)
            phase_gru(u, t, ws, b_ih, b_hh);
        gg.sync();
        // Phase F1: h = relu(LN_ff(snew) @ W1T + b1)
        for (int u = blockIdx.x; u < 256; u += G) {
            gemm_full<256, GF_LN | GF_BIAS | GF_RELU>(sh, t, ws + OFF_SNEW, ws + OFF_W1T,
                              ws + OFF_H, u >> 2, u & 3, g_ff, be_ff, b1p, nullptr, nullptr);
            __syncthreads();
        }
        gg.sync();
        // Phase F2: slots = snew + h @ W2T + b2 (+ dout on last iter)
        for (int u = blockIdx.x; u < 256; u += G) {
            gemm_full<256, GF_BIAS | GF_ADD | GF_OUT>(sh, t, ws + OFF_H, ws + OFF_W2T,
                              ws + OFF_SLOTS, u >> 2, u & 3, nullptr, nullptr, b2p,
                              ws + OFF_SNEW, last ? dout : nullptr);
            __syncthreads();
        }
        gg.sync();
        // Phase G: qt = LN_sl(slots) @ M
        if (!last) {
            for (int u = blockIdx.x; u < 256; u += G) {
                gemm_full<256, GF_LN>(sh, t, ws + OFF_SLOTS, ws + OFF_M, ws + OFF_QT,
                                      u >> 2, u & 3, g_sl, be_sl, nullptr, nullptr, nullptr);
                __syncthreads();
            }
            gg.sync();
        }
    }
}

// ---------------- fallback kernels (same device functions, plain launches) ----------------
__global__ __launch_bounds__(256) void k_attn_fb(const float* __restrict__ x,
                                                 const float* __restrict__ g_in,
                                                 const float* __restrict__ be_in,
                                                 float* __restrict__ ws, int p1) {
    __shared__ MegaShared sh;
    attn_phase(p1 != 0, blockIdx.x, threadIdx.x, x, g_in, be_in, ws, sh);
}
__global__ __launch_bounds__(256) void k_phB_fb(float* __restrict__ ws) {
    __shared__ MegaShared sh;
    int u = blockIdx.x, t = threadIdx.x;
    if (u < 256) phase_upd(sh, t, ws, u >> 2, u & 3);
    else {
        int k = u - 256;
        gemm_full<768, 0>(sh, t, ws + OFF_SLOTS, ws + OFF_WHHT, ws + OFF_GH,
                          k / 12, k % 12, nullptr, nullptr, nullptr, nullptr, nullptr);
    }
}
__global__ __launch_bounds__(256) void k_phC_fb(float* __restrict__ ws) {
    __shared__ MegaShared sh;
    gemm_full<768, 0>(sh, threadIdx.x, ws + OFF_UPD, ws + OFF_WIHT, ws + OFF_GI,
                      blockIdx.x / 12, blockIdx.x % 12, nullptr, nullptr, nullptr, nullptr, nullptr);
}
__global__ __launch_bounds__(256) void k_phD_fb(float* __restrict__ ws,
                                                const float* __restrict__ b_ih,
                                                const float* __restrict__ b_hh) {
    phase_gru(blockIdx.x, threadIdx.x, ws, b_ih, b_hh);
}
__global__ __launch_bounds__(256) void k_phF1_fb(float* __restrict__ ws,
                                                 const float* __restrict__ g_ff,
                                                 const float* __restrict__ be_ff,
                                                 const float* __restrict__ b1p) {
    __shared__ MegaShared sh;
    gemm_full<256, GF_LN | GF_BIAS | GF_RELU>(sh, threadIdx.x, ws + OFF_SNEW, ws + OFF_W1T,
                      ws + OFF_H, blockIdx.x >> 2, blockIdx.x & 3, g_ff, be_ff, b1p, nullptr, nullptr);
}
__global__ __launch_bounds__(256) void k_phF2_fb(float* __restrict__ ws,
                                                 const float* __restrict__ b2p,
                                                 float* __restrict__ dout) {
    __shared__ MegaShared sh;
    gemm_full<256, GF_BIAS | GF_ADD | GF_OUT>(sh, threadIdx.x, ws + OFF_H, ws + OFF_W2T,
                      ws + OFF_SLOTS, blockIdx.x >> 2, blockIdx.x & 3, nullptr, nullptr, b2p,
                      ws + OFF_SNEW, dout);
}
__global__ __launch_bounds__(256) void k_phG_fb(float* __restrict__ ws,
                                                const float* __restrict__ g_sl,
                                                const float* __restrict__ be_sl) {
    __shared__ MegaShared sh;
    gemm_full<256, GF_LN>(sh, threadIdx.x, ws + OFF_SLOTS, ws + OFF_M, ws + OFF_QT,
                          blockIdx.x >> 2, blockIdx.x & 3, g_sl, be_sl, nullptr, nullptr, nullptr);
}

extern "C" void kernel_launch(void* const* d_in, const int* in_sizes, int n_in,
                              void* d_out, int out_size, void* d_ws, size_t ws_size,
                              hipStream_t stream) {
    const float* x      = (const float*)d_in[0];
    const float* noise  = (const float*)d_in[1];
    const float* mu     = (const float*)d_in[2];
    const float* logsig = (const float*)d_in[3];
    const float* Wq     = (const float*)d_in[4];
    const float* Wk     = (const float*)d_in[5];
    const float* Wv     = (const float*)d_in[6];
    const float* W_ih   = (const float*)d_in[7];
    const float* W_hh   = (const float*)d_in[8];
    const float* b_ih   = (const float*)d_in[9];
    const float* b_hh   = (const float*)d_in[10];
    const float* W1     = (const float*)d_in[11];
    const float* b1     = (const float*)d_in[12];
    const float* W2     = (const float*)d_in[13];
    const float* b2     = (const float*)d_in[14];
    const float* g_in   = (const float*)d_in[15];
    const float* be_in  = (const float*)d_in[16];
    const float* g_sl   = (const float*)d_in[17];
    const float* be_sl  = (const float*)d_in[18];
    const float* g_ff   = (const float*)d_in[19];
    const float* be_ff  = (const float*)d_in[20];
    float* ws = (float*)d_ws;
    float* out = (float*)d_out;

    hipLaunchKernelGGL(k_transpose, dim3(24, 8, 5), dim3(256), 0, stream, W_ih, W_hh, Wv, W1, W2, ws);
    hipLaunchKernelGGL(k_m, dim3(256), dim3(256), 0, stream, Wq, Wk, ws);
    hipLaunchKernelGGL(k_init, dim3(512), dim3(256), 0, stream, mu, logsig, noise, ws);
    hipLaunchKernelGGL(k_qt, dim3(4, 64), dim3(256), 0, stream, ws, g_sl, be_sl);

    // ---- size the cooperative grid from MEASURED occupancy ----
    int perCU = 0;
    hipError_t qerr = hipOccupancyMaxActiveBlocksPerMultiprocessor(&perCU, k_mega, 256, 0);
    int grid = 0;
    if (qerr == hipSuccess && perCU > 0) {
        long cap = (long)perCU * 256;   // 256 CUs on MI355X
        if (cap >= 1024)      grid = 1024;
        else if (cap >= 512)  grid = 512;
        else if (cap >= 256)  grid = 256;
    }

    bool launched = false;
    if (grid > 0) {
        void* args[13];
        args[0]  = (void*)&x;
        args[1]  = (void*)&g_in;
        args[2]  = (void*)&be_in;
        args[3]  = (void*)&b_ih;
        args[4]  = (void*)&b_hh;
        args[5]  = (void*)&g_ff;
        args[6]  = (void*)&be_ff;
        args[7]  = (void*)&b1;
        args[8]  = (void*)&b2;
        args[9]  = (void*)&g_sl;
        args[10] = (void*)&be_sl;
        args[11] = (void*)&ws;
        args[12] = (void*)&out;
        hipError_t lerr = hipLaunchCooperativeKernel((const void*)k_mega, dim3(grid), dim3(256),
                                                     args, 0, stream);
        launched = (lerr == hipSuccess);
    }

    if (!launched) {
        // ---- plain-kernel fallback: identical math, more dispatches ----
        for (int it = 0; it < ITERS; ++it) {
            bool last = (it == ITERS - 1);
            hipLaunchKernelGGL(k_attn_fb, dim3(1024), dim3(256), 0, stream, x, g_in, be_in, ws,
                               (it == 0) ? 1 : 0);
            hipLaunchKernelGGL(k_phB_fb, dim3(1024), dim3(256), 0, stream, ws);
            hipLaunchKernelGGL(k_phC_fb, dim3(768), dim3(256), 0, stream, ws);
            hipLaunchKernelGGL(k_phD_fb, dim3(512), dim3(256), 0, stream, ws, b_ih, b_hh);
            hipLaunchKernelGGL(k_phF1_fb, dim3(256), dim3(256), 0, stream, ws, g_ff, be_ff, b1);
            hipLaunchKernelGGL(k_phF2_fb, dim3(256), dim3(256), 0, stream, ws, b2,
                               last ? out : nullptr);
            if (!last)
                hipLaunchKernelGGL(k_phG_fb, dim3(256), dim3(256), 0, stream, ws, g_sl, be_sl);
        }
    }
}

// Round 7
// 2094.281 us; speedup vs baseline: 1.1240x; 1.1240x over previous
//
#include <hip/hip_runtime.h>
#include <cstddef>

#define DIM 256
#define NSLOT 8
#define BATCH 64
#define NTOK 4096
#define SEGB 16                 /* attn blocks per batch */
#define NPART SEGB              /* U/l partials per batch */
#define ITERS 3
#define EPS 1e-5f

typedef short bf16x8 __attribute__((ext_vector_type(8)));
typedef short bf16x4 __attribute__((ext_vector_type(4)));
typedef float f32x4  __attribute__((ext_vector_type(4)));

static __device__ __forceinline__ short f2bf(float f) {
    union { float f; unsigned u; } v; v.f = f;
    unsigned r = v.u + 0x7fffu + ((v.u >> 16) & 1u);   // RNE
    return (short)(r >> 16);
}

// ---------------- workspace layout (float offsets) ----------------
enum : size_t {
    OFF_M     = 0,                               // [256][256]  (Wq^T Wk) * d^-0.5
    OFF_WIHT  = OFF_M    + 256 * 256,            // [256][768]
    OFF_WHHT  = OFF_WIHT + 256 * 768,            // [256][768]
    OFF_WVT   = OFF_WHHT + 256 * 768,            // [256][256]
    OFF_W1T   = OFF_WVT  + 256 * 256,            // [256][256]
    OFF_W2T   = OFF_W1T  + 256 * 256,            // [256][256]
    OFF_SLOTS = OFF_W2T  + 256 * 256,            // [512][256]
    OFF_SNEW  = OFF_SLOTS + BATCH * NSLOT * 256, // (unused, layout kept)
    OFF_QT    = OFF_SNEW  + BATCH * NSLOT * 256, // [512][256]
    OFF_H     = OFF_QT    + BATCH * NSLOT * 256, // (unused)
    OFF_UPD   = OFF_H     + BATCH * NSLOT * 256, // counters: int[3][64] at base
    OFF_UPART = OFF_UPD   + BATCH * NSLOT * 256, // [64][NPART][8][256]
    OFF_LPART = OFF_UPART + (size_t)BATCH * NPART * NSLOT * 256, // [64][NPART][16] (l:0-7)
    OFF_XLN   = OFF_LPART + BATCH * NPART * 16,  // bf16 LN(x) token-major [64][4096][256]
    WS_FLOATS = OFF_XLN   + (size_t)BATCH * NTOK * 128
};

// ---------------- shared union: attn phase (39424 B) / slot-chain tail (24.6 KB) ----------------
union MegaShared {
    struct {
        short qhi[8 * 264];
        short xT[256 * 64];
        short Etmp[16 * 72];
        float lsum[4][8];
    } a;
    struct {
        float uc[8][256];   // combined updates -> snew
        float sl[8][256];   // old slots -> h
        float t1[8][256];   // raw sums -> upd -> lnb -> slots_out
        float lsum8[8];
    } tl;
};

// ---------------- merged prologue: transposes + M + slots-init + counter zero ----------------
__global__ __launch_bounds__(256) void k_pre(const float* __restrict__ w_ih,
                                             const float* __restrict__ w_hh,
                                             const float* __restrict__ wv,
                                             const float* __restrict__ w1,
                                             const float* __restrict__ w2,
                                             const float* __restrict__ wq,
                                             const float* __restrict__ wk,
                                             const float* __restrict__ mu,
                                             const float* __restrict__ logsig,
                                             const float* __restrict__ noise,
                                             float* __restrict__ ws) {
    int u = blockIdx.x, t = threadIdx.x;
    if (u < 576) {
        const float* src; float* dst; int R, idx;
        if (u < 192)      { src = w_ih; dst = ws + OFF_WIHT; R = 768; idx = u; }
        else if (u < 384) { src = w_hh; dst = ws + OFF_WHHT; R = 768; idx = u - 192; }
        else if (u < 448) { src = wv;   dst = ws + OFF_WVT;  R = 256; idx = u - 384; }
        else if (u < 512) { src = w1;   dst = ws + OFF_W1T;  R = 256; idx = u - 448; }
        else              { src = w2;   dst = ws + OFF_W2T;  R = 256; idx = u - 512; }
        int bx = idx >> 3, by = idx & 7;
        __shared__ float tile[32][33];
        int lx = t & 31, ly = t >> 5;
        int r0 = bx * 32, c0 = by * 32;
#pragma unroll
        for (int p = 0; p < 4; ++p)
            tile[ly + p * 8][lx] = src[(size_t)(r0 + ly + p * 8) * 256 + c0 + lx];
        __syncthreads();
#pragma unroll
        for (int p = 0; p < 4; ++p)
            dst[(size_t)(c0 + ly + p * 8) * R + r0 + lx] = tile[lx][ly + p * 8];
    } else if (u < 832) {
        int d = u - 576;
        if (d == 0 && t < 192) ((int*)(ws + OFF_UPD))[t] = 0;   // zero tail counters
        float acc = 0.f;
        for (int e = 0; e < 256; ++e)
            acc += wq[e * 256 + d] * wk[e * 256 + t];
        ws[OFF_M + d * 256 + t] = acc * 0.0625f; // 256^-0.5
    } else {
        int i = (u - 832) * 256 + t;             // 512 blocks -> 131072
        int d = i & 255;
        ws[OFF_SLOTS + i] = mu[d] + noise[i] * __expf(logsig[d]);
    }
}

// ---------------- qt = LN(slots, g_sl) @ M  (prologue only) ----------------
__global__ __launch_bounds__(256) void k_qt(float* __restrict__ ws,
                                            const float* __restrict__ g_sl,
                                            const float* __restrict__ be_sl) {
    __shared__ float ln[2048];
    int chunk = blockIdx.x, b = blockIdx.y;
    int t = threadIdx.x, wave = t >> 6, lane = t & 63;
    const float* slots = ws + OFF_SLOTS + b * 2048;
    float4 gf = ((const float4*)g_sl)[lane];
    float4 bf = ((const float4*)be_sl)[lane];
#pragma unroll
    for (int rr = 0; rr < 2; ++rr) {
        int r = wave + rr * 4;
        float4 v = ((const float4*)(slots + r * 256))[lane];
        float s1 = v.x + v.y + v.z + v.w;
        float s2 = v.x * v.x + v.y * v.y + v.z * v.z + v.w * v.w;
#pragma unroll
        for (int m = 1; m < 64; m <<= 1) { s1 += __shfl_xor(s1, m); s2 += __shfl_xor(s2, m); }
        float mu = s1 * (1.f / 256.f);
        float rstd = rsqrtf(s2 * (1.f / 256.f) - mu * mu + EPS);
        float4 o;
        o.x = (v.x - mu) * rstd * gf.x + bf.x;
        o.y = (v.y - mu) * rstd * gf.y + bf.y;
        o.z = (v.z - mu) * rstd * gf.z + bf.z;
        o.w = (v.w - mu) * rstd * gf.w + bf.w;
        *((float4*)&ln[r * 256 + lane * 4]) = o;
    }
    __syncthreads();
    const float* M = ws + OFF_M;
    int k0 = t >> 6;
    int e = chunk * 64 + (t & 63);
    float a0 = 0.f, a1 = 0.f;
    for (int d = 0; d < 256; ++d) {
        float m = M[d * 256 + e];
        a0 += ln[k0 * 256 + d] * m;
        a1 += ln[(k0 + 4) * 256 + d] * m;
    }
    float* qt = ws + OFF_QT + b * 2048;
    qt[k0 * 256 + e] = a0;
    qt[(k0 + 4) * 256 + e] = a1;
}

// ---------------- wave-per-2-rows LN over [8][256] LDS ----------------
static __device__ __forceinline__ void ln8(const float (*__restrict__ src)[256],
                                           float (*__restrict__ dst)[256],
                                           const float* __restrict__ g,
                                           const float* __restrict__ be, int t) {
    int wv = t >> 6, lane = t & 63;
    float4 gf = ((const float4*)g)[lane];
    float4 bf = ((const float4*)be)[lane];
#pragma unroll
    for (int rr = 0; rr < 2; ++rr) {
        int r = wv + rr * 4;
        float4 v = *(const float4*)&src[r][lane * 4];
        float s1 = v.x + v.y + v.z + v.w;
        float s2 = v.x * v.x + v.y * v.y + v.z * v.z + v.w * v.w;
#pragma unroll
        for (int m = 1; m < 64; m <<= 1) { s1 += __shfl_xor(s1, m); s2 += __shfl_xor(s2, m); }
        float mu = s1 * (1.f / 256.f);
        float rstd = rsqrtf(s2 * (1.f / 256.f) - mu * mu + EPS);
        float4 o;
        o.x = (v.x - mu) * rstd * gf.x + bf.x;
        o.y = (v.y - mu) * rstd * gf.y + bf.y;
        o.z = (v.z - mu) * rstd * gf.z + bf.z;
        o.w = (v.w - mu) * rstd * gf.w + bf.w;
        *(float4*)&dst[r][lane * 4] = o;
    }
}

// ---------------- attention pass (R3-proven) + last-block slot-chain tail ----------------
template <int IT>
__global__ __launch_bounds__(256) void k_attn_it(
        const float* __restrict__ x,
        const float* __restrict__ g_in, const float* __restrict__ be_in,
        const float* __restrict__ b_ih, const float* __restrict__ b_hh,
        const float* __restrict__ g_ff, const float* __restrict__ be_ff,
        const float* __restrict__ b1p, const float* __restrict__ b2p,
        const float* __restrict__ g_sl, const float* __restrict__ be_sl,
        float* __restrict__ ws, float* __restrict__ dout) {
    constexpr bool p1 = (IT == 0);
    constexpr bool last = (IT == ITERS - 1);
    __shared__ MegaShared sh;
    __shared__ int lastflag;

    int seg = blockIdx.x, b = blockIdx.y;
    int t = threadIdx.x;
    int w = t >> 6, lane = t & 63;
    int q = lane >> 4, s16 = lane & 15;

    const float* qtg = ws + OFF_QT + b * 2048;
    for (int idx = t; idx < 8 * 264; idx += 256) {
        int s = idx / 264;
        int d = idx - s * 264;
        sh.a.qhi[idx] = (d < 256) ? f2bf(qtg[s * 256 + d]) : (short)0;
    }
    __syncthreads();

    bf16x8 qf[8];
#pragma unroll
    for (int i = 0; i < 8; ++i) {
        if (s16 < 8) qf[i] = *(const bf16x8*)&sh.a.qhi[s16 * 264 + i * 32 + q * 8];
        else         qf[i] = (bf16x8){0, 0, 0, 0, 0, 0, 0, 0};
    }

    f32x4 U[4];
#pragma unroll
    for (int c = 0; c < 4; ++c) U[c] = (f32x4){0.f, 0.f, 0.f, 0.f};
    float lacc = 0.f;

    short* xln = (short*)(ws + OFF_XLN);
    int mytok = seg * 256 + w * 16 + s16;
    int g0 = ((w * 16 + s16) >> 3);
    int t7 = s16 & 7;

    bf16x8 af[8];
    if (!p1) {
        const short* xr = xln + ((size_t)b * NTOK + mytok) * 256 + q * 8;
#pragma unroll
        for (int i = 0; i < 8; ++i) af[i] = *(const bf16x8*)&xr[i * 32];
    }

    for (int tt = 0; tt < 4; ++tt) {
        int tok = mytok + tt * 64;
        if (p1) {
            const float4* xp = (const float4*)(x + ((size_t)b * NTOK + tok) * 256 + q * 8);
            float s1 = 0.f, s2 = 0.f;
#pragma unroll
            for (int i = 0; i < 8; ++i) {          // stats pass (values re-read below via L1)
                float4 a = xp[8 * i], bv = xp[8 * i + 1];
                s1 += a.x + a.y + a.z + a.w + bv.x + bv.y + bv.z + bv.w;
                s2 += a.x * a.x + a.y * a.y + a.z * a.z + a.w * a.w
                    + bv.x * bv.x + bv.y * bv.y + bv.z * bv.z + bv.w * bv.w;
            }
            s1 += __shfl_xor(s1, 16); s2 += __shfl_xor(s2, 16);
            s1 += __shfl_xor(s1, 32); s2 += __shfl_xor(s2, 32);
            float mu = s1 * (1.f / 256.f);
            float rstd = rsqrtf(s2 * (1.f / 256.f) - mu * mu + EPS);
            short* xrow = xln + ((size_t)b * NTOK + tok) * 256;
#pragma unroll
            for (int i = 0; i < 8; ++i) {
                float4 a = xp[8 * i], bv = xp[8 * i + 1];
                int dbase = i * 32 + q * 8;
                float4 gA = *(const float4*)&g_in[dbase];
                float4 gB = *(const float4*)&g_in[dbase + 4];
                float4 bA = *(const float4*)&be_in[dbase];
                float4 bB = *(const float4*)&be_in[dbase + 4];
                bf16x8 f;
                f[0] = f2bf((a.x - mu) * rstd * gA.x + bA.x);
                f[1] = f2bf((a.y - mu) * rstd * gA.y + bA.y);
                f[2] = f2bf((a.z - mu) * rstd * gA.z + bA.z);
                f[3] = f2bf((a.w - mu) * rstd * gA.w + bA.w);
                f[4] = f2bf((bv.x - mu) * rstd * gB.x + bB.x);
                f[5] = f2bf((bv.y - mu) * rstd * gB.y + bB.y);
                f[6] = f2bf((bv.z - mu) * rstd * gB.z + bB.z);
                f[7] = f2bf((bv.w - mu) * rstd * gB.w + bB.w);
                af[i] = f;
                *(bf16x8*)&xrow[dbase] = f;
            }
        }

        // ---- QK^T: two independent MFMA chains ----
        f32x4 Lc0 = (f32x4){0.f, 0.f, 0.f, 0.f};
        f32x4 Lc1 = (f32x4){0.f, 0.f, 0.f, 0.f};
#pragma unroll
        for (int i = 0; i < 4; ++i) {
            Lc0 = __builtin_amdgcn_mfma_f32_16x16x32_bf16(af[i],     qf[i],     Lc0, 0, 0, 0);
            Lc1 = __builtin_amdgcn_mfma_f32_16x16x32_bf16(af[i + 4], qf[i + 4], Lc1, 0, 0, 0);
        }

        bf16x4 e2;
#pragma unroll
        for (int r = 0; r < 4; ++r) {
            float E = __expf(fminf(Lc0[r] + Lc1[r], 30.f));
            lacc += E;
            e2[r] = f2bf(E);
        }

        __syncthreads();   // (A) previous tile's xT/Etmp reads complete

#pragma unroll
        for (int i = 0; i < 8; ++i) {
            int Ki = (4 * i + q) & 7;
            int dbase = i * 32 + q * 8;
            bf16x8 f = af[i];
#pragma unroll
            for (int e = 0; e < 8; ++e) {
                int gp = (g0 ^ e ^ Ki) & 7;
                sh.a.xT[((dbase + e) << 6) + (gp << 3) + t7] = f[e];
            }
        }
        *(bf16x4*)&sh.a.Etmp[s16 * 72 + w * 16 + q * 4] = e2;

        __syncthreads();   // (B) xT + Etmp ready; af now dead

        // ---- prefetch next tile's A-frags INTO af ----
        if (!p1 && tt < 3) {
            const short* xr = xln + ((size_t)b * NTOK + tok + 64) * 256 + q * 8;
#pragma unroll
            for (int i = 0; i < 8; ++i) af[i] = *(const bf16x8*)&xr[i * 32];
        }

        bf16x8 ea0 = *(const bf16x8*)&sh.a.Etmp[s16 * 72 + q * 8];
        bf16x8 ea1 = *(const bf16x8*)&sh.a.Etmp[s16 * 72 + 32 + q * 8];
#pragma unroll
        for (int c = 0; c < 4; ++c) {
            int d = (4 * w + c) * 16 + s16;
            int swz = (d ^ (d >> 3)) & 7;
            const short* row = &sh.a.xT[d << 6];
            bf16x8 b0 = *(const bf16x8*)&row[((q ^ swz) & 7) << 3];
            bf16x8 b1 = *(const bf16x8*)&row[(((4 + q) ^ swz) & 7) << 3];
            U[c] = __builtin_amdgcn_mfma_f32_16x16x32_bf16(ea0, b0, U[c], 0, 0, 0);
            U[c] = __builtin_amdgcn_mfma_f32_16x16x32_bf16(ea1, b1, U[c], 0, 0, 0);
        }
    }

    // ---- store l and U partials ----
    lacc += __shfl_xor(lacc, 16); lacc += __shfl_xor(lacc, 32);
    __syncthreads();
    if (q == 0 && s16 < 8) sh.a.lsum[w][s16] = lacc;
    __syncthreads();
    float* lpart = ws + OFF_LPART + (size_t)(b * NPART + seg) * 16;
    if (t < 8) lpart[t] = sh.a.lsum[0][t] + sh.a.lsum[1][t] + sh.a.lsum[2][t] + sh.a.lsum[3][t];
    float* up = ws + OFF_UPART + (size_t)(b * NPART + seg) * NSLOT * 256;
#pragma unroll
    for (int c = 0; c < 4; ++c) {
        int d = (4 * w + c) * 16 + s16;
#pragma unroll
        for (int r = 0; r < 4; ++r) {
            int slot = q * 4 + r;
            if (slot < 8) up[slot * 256 + d] = U[c][r];
        }
    }

    // ---- last-block election (device-scope fence + atomic; guide G12/G16) ----
    if (t == 0) lastflag = 0;
    __threadfence();                 // release my partial stores device-wide
    __syncthreads();                 // all threads' fences done; lastflag init visible
    int* cnt = (int*)(ws + OFF_UPD) + IT * 64 + b;
    if (t == 0) {
        if (atomicAdd(cnt, 1) == NPART - 1) lastflag = 1;
    }
    __syncthreads();
    if (!lastflag) return;
    __threadfence();                 // acquire: see all other blocks' partials
    if (t == 0) *cnt = 0;            // defensive reset (robust to missing re-zero)

    // ================= slot-chain tail (batch b; math identical to R3 k_fused) =================
    // Stage 0: combine l + raw-U partials; load old slots
    if (t < 8) {
        float l = 0.f;
        for (int g = 0; g < NPART; ++g)
            l += ws[OFF_LPART + (size_t)(b * NPART + g) * 16 + t];
        sh.tl.lsum8[t] = l;
    }
#pragma unroll
    for (int s = 0; s < 8; ++s) {
        float a = 0.f;
        const float* base = ws + OFF_UPART + (size_t)b * (NPART * 2048) + s * 256 + t;
        for (int g = 0; g < NPART; ++g) a += base[(size_t)g * 2048];
        sh.tl.t1[s][t] = a;
        sh.tl.sl[s][t] = ws[OFF_SLOTS + (size_t)b * 2048 + s * 256 + t];
    }
    __syncthreads();
#pragma unroll
    for (int s = 0; s < 8; ++s) sh.tl.uc[s][t] = sh.tl.t1[s][t] / sh.tl.lsum8[s];
    __syncthreads();

    // Stage 1: upd = uc @ WvT -> t1
    {
        const float* W = ws + OFF_WVT;
        float acc[8] = {0.f, 0.f, 0.f, 0.f, 0.f, 0.f, 0.f, 0.f};
        for (int dd = 0; dd < 256; ++dd) {
            float wv = W[dd * 256 + t];
#pragma unroll
            for (int s = 0; s < 8; ++s) acc[s] += sh.tl.uc[s][dd] * wv;
        }
        __syncthreads();
#pragma unroll
        for (int s = 0; s < 8; ++s) sh.tl.t1[s][t] = acc[s];
    }
    __syncthreads();

    // Stage 2: GRU (2 slots per pass; t1=upd, sl=old slots -> snew into uc)
    {
        const float* WI = ws + OFF_WIHT;
        const float* WH = ws + OFF_WHHT;
        float bi0 = b_ih[t], bi1 = b_ih[256 + t], bi2 = b_ih[512 + t];
        float bh0 = b_hh[t], bh1 = b_hh[256 + t], bh2 = b_hh[512 + t];
        for (int p = 0; p < 4; ++p) {
            int sA = 2 * p, sB = 2 * p + 1;
            float ar0 = 0.f, az0 = 0.f, an0 = 0.f, hr0 = 0.f, hz0 = 0.f, hn0 = 0.f;
            float ar1 = 0.f, az1 = 0.f, an1 = 0.f, hr1 = 0.f, hz1 = 0.f, hn1 = 0.f;
            for (int dd = 0; dd < 256; ++dd) {
                const float* wi = WI + (size_t)dd * 768;
                const float* wh = WH + (size_t)dd * 768;
                float wi0 = wi[t], wi1 = wi[256 + t], wi2 = wi[512 + t];
                float wh0 = wh[t], wh1 = wh[256 + t], wh2 = wh[512 + t];
                float u0 = sh.tl.t1[sA][dd], u1 = sh.tl.t1[sB][dd];
                float v0 = sh.tl.sl[sA][dd], v1 = sh.tl.sl[sB][dd];
                ar0 += u0 * wi0; az0 += u0 * wi1; an0 += u0 * wi2;
                hr0 += v0 * wh0; hz0 += v0 * wh1; hn0 += v0 * wh2;
                ar1 += u1 * wi0; az1 += u1 * wi1; an1 += u1 * wi2;
                hr1 += v1 * wh0; hz1 += v1 * wh1; hn1 += v1 * wh2;
            }
            float rg0 = 1.f / (1.f + __expf(-(ar0 + bi0 + hr0 + bh0)));
            float zg0 = 1.f / (1.f + __expf(-(az0 + bi1 + hz0 + bh1)));
            float ng0 = tanhf(an0 + bi2 + rg0 * (hn0 + bh2));
            sh.tl.uc[sA][t] = (1.f - zg0) * ng0 + zg0 * sh.tl.sl[sA][t];
            float rg1 = 1.f / (1.f + __expf(-(ar1 + bi0 + hr1 + bh0)));
            float zg1 = 1.f / (1.f + __expf(-(az1 + bi1 + hz1 + bh1)));
            float ng1 = tanhf(an1 + bi2 + rg1 * (hn1 + bh2));
            sh.tl.uc[sB][t] = (1.f - zg1) * ng1 + zg1 * sh.tl.sl[sB][t];
        }
    }
    __syncthreads();   // snew (in uc) ready

    // Stage 3: lnb = LN_ff(snew) -> t1
    ln8(sh.tl.uc, sh.tl.t1, g_ff, be_ff, t);
    __syncthreads();

    // Stage 4: h = relu(lnb @ W1T + b1) -> sl
    {
        const float* W = ws + OFF_W1T;
        float acc[8] = {0.f, 0.f, 0.f, 0.f, 0.f, 0.f, 0.f, 0.f};
        for (int dd = 0; dd < 256; ++dd) {
            float wv = W[dd * 256 + t];
#pragma unroll
            for (int s = 0; s < 8; ++s) acc[s] += sh.tl.t1[s][dd] * wv;
        }
        __syncthreads();
        float bb = b1p[t];
#pragma unroll
        for (int s = 0; s < 8; ++s) sh.tl.sl[s][t] = fmaxf(acc[s] + bb, 0.f);
    }
    __syncthreads();

    // Stage 5: slots_out = snew + h @ W2T + b2 -> t1 + global (+dout on last)
    {
        const float* W = ws + OFF_W2T;
        float acc[8] = {0.f, 0.f, 0.f, 0.f, 0.f, 0.f, 0.f, 0.f};
        for (int dd = 0; dd < 256; ++dd) {
            float wv = W[dd * 256 + t];
#pragma unroll
            for (int s = 0; s < 8; ++s) acc[s] += sh.tl.sl[s][dd] * wv;
        }
        __syncthreads();
        float bb = b2p[t];
#pragma unroll
        for (int s = 0; s < 8; ++s) {
            float r = sh.tl.uc[s][t] + acc[s] + bb;
            sh.tl.t1[s][t] = r;
            ws[OFF_SLOTS + (size_t)b * 2048 + s * 256 + t] = r;
            if (last) dout[(size_t)b * 2048 + s * 256 + t] = r;
        }
    }

    // Stage 6 (non-final iters): qt = LN_sl(slots_out) @ M
    if (!last) {
        __syncthreads();
        ln8(sh.tl.t1, sh.tl.uc, g_sl, be_sl, t);
        __syncthreads();
        const float* M = ws + OFF_M;
        float acc[8] = {0.f, 0.f, 0.f, 0.f, 0.f, 0.f, 0.f, 0.f};
        for (int dd = 0; dd < 256; ++dd) {
            float m = M[dd * 256 + t];
#pragma unroll
            for (int s = 0; s < 8; ++s) acc[s] += sh.tl.uc[s][dd] * m;
        }
#pragma unroll
        for (int s = 0; s < 8; ++s)
            ws[OFF_QT + (size_t)b * 2048 + s * 256 + t] = acc[s];
    }
}

extern "C" void kernel_launch(void* const* d_in, const int* in_sizes, int n_in,
                              void* d_out, int out_size, void* d_ws, size_t ws_size,
                              hipStream_t stream) {
    const float* x      = (const float*)d_in[0];
    const float* noise  = (const float*)d_in[1];
    const float* mu     = (const float*)d_in[2];
    const float* logsig = (const float*)d_in[3];
    const float* Wq     = (const float*)d_in[4];
    const float* Wk     = (const float*)d_in[5];
    const float* Wv     = (const float*)d_in[6];
    const float* W_ih   = (const float*)d_in[7];
    const float* W_hh   = (const float*)d_in[8];
    const float* b_ih   = (const float*)d_in[9];
    const float* b_hh   = (const float*)d_in[10];
    const float* W1     = (const float*)d_in[11];
    const float* b1     = (const float*)d_in[12];
    const float* W2     = (const float*)d_in[13];
    const float* b2     = (const float*)d_in[14];
    const float* g_in   = (const float*)d_in[15];
    const float* be_in  = (const float*)d_in[16];
    const float* g_sl   = (const float*)d_in[17];
    const float* be_sl  = (const float*)d_in[18];
    const float* g_ff   = (const float*)d_in[19];
    const float* be_ff  = (const float*)d_in[20];
    float* ws = (float*)d_ws;
    float* out = (float*)d_out;

    hipLaunchKernelGGL(k_pre, dim3(1344), dim3(256), 0, stream,
                       W_ih, W_hh, Wv, W1, W2, Wq, Wk, mu, logsig, noise, ws);
    hipLaunchKernelGGL(k_qt, dim3(4, 64), dim3(256), 0, stream, ws, g_sl, be_sl);

    hipLaunchKernelGGL((k_attn_it<0>), dim3(SEGB, 64), dim3(256), 0, stream,
                       x, g_in, be_in, b_ih, b_hh, g_ff, be_ff, b1, b2, g_sl, be_sl, ws, out);
    hipLaunchKernelGGL((k_attn_it<1>), dim3(SEGB, 64), dim3(256), 0, stream,
                       x, g_in, be_in, b_ih, b_hh, g_ff, be_ff, b1, b2, g_sl, be_sl, ws, out);
    hipLaunchKernelGGL((k_attn_it<2>), dim3(SEGB, 64), dim3(256), 0, stream,
                       x, g_in, be_in, b_ih, b_hh, g_ff, be_ff, b1, b2, g_sl, be_sl, ws, out);
}

// Round 8
// 728.324 us; speedup vs baseline: 3.2321x; 2.8755x over previous
//
#include <hip/hip_runtime.h>
#include <cstddef>

#define DIM 256
#define NSLOT 8
#define BATCH 64
#define NTOK 4096
#define SEGB 16                 /* attn blocks per batch */
#define NPART SEGB              /* U/l partials per batch */
#define ITERS 3
#define EPS 1e-5f

typedef short bf16x8 __attribute__((ext_vector_type(8)));
typedef short bf16x4 __attribute__((ext_vector_type(4)));
typedef float f32x4  __attribute__((ext_vector_type(4)));

static __device__ __forceinline__ short f2bf(float f) {
    union { float f; unsigned u; } v; v.f = f;
    unsigned r = v.u + 0x7fffu + ((v.u >> 16) & 1u);   // RNE
    return (short)(r >> 16);
}

// ---------------- workspace layout (float offsets) ----------------
enum : size_t {
    OFF_M     = 0,                               // [256][256]  (Wq^T Wk) * d^-0.5
    OFF_WIHT  = OFF_M    + 256 * 256,            // [256][768]
    OFF_WHHT  = OFF_WIHT + 256 * 768,            // [256][768]
    OFF_WVT   = OFF_WHHT + 256 * 768,            // [256][256]
    OFF_W1T   = OFF_WVT  + 256 * 256,            // [256][256]
    OFF_W2T   = OFF_W1T  + 256 * 256,            // [256][256]
    OFF_SLOTS = OFF_W2T  + 256 * 256,            // [512][256]
    OFF_SNEW  = OFF_SLOTS + BATCH * NSLOT * 256, // (unused, layout kept)
    OFF_QT    = OFF_SNEW  + BATCH * NSLOT * 256, // [512][256]
    OFF_H     = OFF_QT    + BATCH * NSLOT * 256, // (unused)
    OFF_UPD   = OFF_H     + BATCH * NSLOT * 256, // (unused)
    OFF_UPART = OFF_UPD   + BATCH * NSLOT * 256, // [64][NPART][8][256]
    OFF_LPART = OFF_UPART + (size_t)BATCH * NPART * NSLOT * 256, // [64][NPART][16] (l:0-7)
    OFF_XLN   = OFF_LPART + BATCH * NPART * 16,  // bf16 LN(x) token-major [64][4096][256]
    WS_FLOATS = OFF_XLN   + (size_t)BATCH * NTOK * 128
};

// ---------------- merged prologue: weight transposes + M + slots-init (R7-verified) ----------------
__global__ __launch_bounds__(256) void k_pre(const float* __restrict__ w_ih,
                                             const float* __restrict__ w_hh,
                                             const float* __restrict__ wv,
                                             const float* __restrict__ w1,
                                             const float* __restrict__ w2,
                                             const float* __restrict__ wq,
                                             const float* __restrict__ wk,
                                             const float* __restrict__ mu,
                                             const float* __restrict__ logsig,
                                             const float* __restrict__ noise,
                                             float* __restrict__ ws) {
    int u = blockIdx.x, t = threadIdx.x;
    if (u < 576) {
        const float* src; float* dst; int R, idx;
        if (u < 192)      { src = w_ih; dst = ws + OFF_WIHT; R = 768; idx = u; }
        else if (u < 384) { src = w_hh; dst = ws + OFF_WHHT; R = 768; idx = u - 192; }
        else if (u < 448) { src = wv;   dst = ws + OFF_WVT;  R = 256; idx = u - 384; }
        else if (u < 512) { src = w1;   dst = ws + OFF_W1T;  R = 256; idx = u - 448; }
        else              { src = w2;   dst = ws + OFF_W2T;  R = 256; idx = u - 512; }
        int bx = idx >> 3, by = idx & 7;
        __shared__ float tile[32][33];
        int lx = t & 31, ly = t >> 5;
        int r0 = bx * 32, c0 = by * 32;
#pragma unroll
        for (int p = 0; p < 4; ++p)
            tile[ly + p * 8][lx] = src[(size_t)(r0 + ly + p * 8) * 256 + c0 + lx];
        __syncthreads();
#pragma unroll
        for (int p = 0; p < 4; ++p)
            dst[(size_t)(c0 + ly + p * 8) * R + r0 + lx] = tile[lx][ly + p * 8];
    } else if (u < 832) {
        int d = u - 576;
        float acc = 0.f;
        for (int e = 0; e < 256; ++e)
            acc += wq[e * 256 + d] * wk[e * 256 + t];
        ws[OFF_M + d * 256 + t] = acc * 0.0625f; // 256^-0.5
    } else {
        int i = (u - 832) * 256 + t;             // 512 blocks -> 131072
        int d = i & 255;
        ws[OFF_SLOTS + i] = mu[d] + noise[i] * __expf(logsig[d]);
    }
}

// ---------------- qt = LN(slots, g_sl) @ M  (prologue only) ----------------
__global__ __launch_bounds__(256) void k_qt(float* __restrict__ ws,
                                            const float* __restrict__ g_sl,
                                            const float* __restrict__ be_sl) {
    __shared__ float ln[2048];
    int chunk = blockIdx.x, b = blockIdx.y;
    int t = threadIdx.x, wave = t >> 6, lane = t & 63;
    const float* slots = ws + OFF_SLOTS + b * 2048;
    float4 gf = ((const float4*)g_sl)[lane];
    float4 bf = ((const float4*)be_sl)[lane];
#pragma unroll
    for (int rr = 0; rr < 2; ++rr) {
        int r = wave + rr * 4;
        float4 v = ((const float4*)(slots + r * 256))[lane];
        float s1 = v.x + v.y + v.z + v.w;
        float s2 = v.x * v.x + v.y * v.y + v.z * v.z + v.w * v.w;
#pragma unroll
        for (int m = 1; m < 64; m <<= 1) { s1 += __shfl_xor(s1, m); s2 += __shfl_xor(s2, m); }
        float mu = s1 * (1.f / 256.f);
        float rstd = rsqrtf(s2 * (1.f / 256.f) - mu * mu + EPS);
        float4 o;
        o.x = (v.x - mu) * rstd * gf.x + bf.x;
        o.y = (v.y - mu) * rstd * gf.y + bf.y;
        o.z = (v.z - mu) * rstd * gf.z + bf.z;
        o.w = (v.w - mu) * rstd * gf.w + bf.w;
        *((float4*)&ln[r * 256 + lane * 4]) = o;
    }
    __syncthreads();
    const float* M = ws + OFF_M;
    int k0 = t >> 6;               // wave-uniform
    int e = chunk * 64 + (t & 63);
    float a0 = 0.f, a1 = 0.f;
    for (int d = 0; d < 256; ++d) {
        float m = M[d * 256 + e];
        a0 += ln[k0 * 256 + d] * m;
        a1 += ln[(k0 + 4) * 256 + d] * m;
    }
    float* qt = ws + OFF_QT + b * 2048;
    qt[k0 * 256 + e] = a0;
    qt[(k0 + 4) * 256 + e] = a1;
}

// ---------------- MFMA flash attention, single bf16 copy (R3-proven, 732 us config) ----------------
template <bool P1>
__global__ __launch_bounds__(256) void k_attn_t(const float* __restrict__ x,
                                                const float* __restrict__ g_in,
                                                const float* __restrict__ be_in,
                                                float* __restrict__ ws) {
    int seg = blockIdx.x, b = blockIdx.y;
    int t = threadIdx.x;
    int w = t >> 6, lane = t & 63;
    int q = lane >> 4, s16 = lane & 15;

    __shared__ short qhi[8 * 264];       // bf16 qt (8 real slots only)
    __shared__ short xT[256 * 64];       // bf16 transpose tile, XOR-swizzled groups
    __shared__ short Etmp[16 * 72];      // E bf16, [slot][token]
    __shared__ float lsum[4][8];

    const float* qtg = ws + OFF_QT + b * 2048;
    for (int idx = t; idx < 8 * 264; idx += 256) {
        int s = idx / 264;
        int d = idx - s * 264;
        qhi[idx] = (d < 256) ? f2bf(qtg[s * 256 + d]) : (short)0;
    }
    __syncthreads();

    bf16x8 qf[8];
#pragma unroll
    for (int i = 0; i < 8; ++i) {
        if (s16 < 8) qf[i] = *(const bf16x8*)&qhi[s16 * 264 + i * 32 + q * 8];
        else         qf[i] = (bf16x8){0, 0, 0, 0, 0, 0, 0, 0};
    }

    f32x4 U[4];
#pragma unroll
    for (int c = 0; c < 4; ++c) U[c] = (f32x4){0.f, 0.f, 0.f, 0.f};
    float lacc = 0.f;

    short* xln = (short*)(ws + OFF_XLN);
    int mytok = seg * 256 + w * 16 + s16;
    int g0 = ((w * 16 + s16) >> 3);
    int t7 = s16 & 7;

    bf16x8 af[8];
    if (!P1) {
        const short* xr = xln + ((size_t)b * NTOK + mytok) * 256 + q * 8;
#pragma unroll
        for (int i = 0; i < 8; ++i) af[i] = *(const bf16x8*)&xr[i * 32];
    }

    for (int tt = 0; tt < 4; ++tt) {
        int tok = mytok + tt * 64;
        if (P1) {
            // ---- fp32 load + LN + bf16 convert + write xln ----
            const float4* xp = (const float4*)(x + ((size_t)b * NTOK + tok) * 256 + q * 8);
            float4 xa[8], xb[8];
#pragma unroll
            for (int i = 0; i < 8; ++i) { xa[i] = xp[8 * i]; xb[i] = xp[8 * i + 1]; }
            float s1 = 0.f, s2 = 0.f;
#pragma unroll
            for (int i = 0; i < 8; ++i) {
                s1 += xa[i].x + xa[i].y + xa[i].z + xa[i].w + xb[i].x + xb[i].y + xb[i].z + xb[i].w;
                s2 += xa[i].x * xa[i].x + xa[i].y * xa[i].y + xa[i].z * xa[i].z + xa[i].w * xa[i].w
                    + xb[i].x * xb[i].x + xb[i].y * xb[i].y + xb[i].z * xb[i].z + xb[i].w * xb[i].w;
            }
            s1 += __shfl_xor(s1, 16); s2 += __shfl_xor(s2, 16);
            s1 += __shfl_xor(s1, 32); s2 += __shfl_xor(s2, 32);
            float mu = s1 * (1.f / 256.f);
            float rstd = rsqrtf(s2 * (1.f / 256.f) - mu * mu + EPS);
            short* xrow = xln + ((size_t)b * NTOK + tok) * 256;
#pragma unroll
            for (int i = 0; i < 8; ++i) {
                int dbase = i * 32 + q * 8;
                float4 gA = *(const float4*)&g_in[dbase];
                float4 gB = *(const float4*)&g_in[dbase + 4];
                float4 bA = *(const float4*)&be_in[dbase];
                float4 bB = *(const float4*)&be_in[dbase + 4];
                bf16x8 f;
                f[0] = f2bf((xa[i].x - mu) * rstd * gA.x + bA.x);
                f[1] = f2bf((xa[i].y - mu) * rstd * gA.y + bA.y);
                f[2] = f2bf((xa[i].z - mu) * rstd * gA.z + bA.z);
                f[3] = f2bf((xa[i].w - mu) * rstd * gA.w + bA.w);
                f[4] = f2bf((xb[i].x - mu) * rstd * gB.x + bB.x);
                f[5] = f2bf((xb[i].y - mu) * rstd * gB.y + bB.y);
                f[6] = f2bf((xb[i].z - mu) * rstd * gB.z + bB.z);
                f[7] = f2bf((xb[i].w - mu) * rstd * gB.w + bB.w);
                af[i] = f;
                *(bf16x8*)&xrow[i * 32 + q * 8] = f;
            }
        }

        // ---- QK^T: two independent MFMA chains ----
        f32x4 Lc0 = (f32x4){0.f, 0.f, 0.f, 0.f};
        f32x4 Lc1 = (f32x4){0.f, 0.f, 0.f, 0.f};
#pragma unroll
        for (int i = 0; i < 4; ++i) {
            Lc0 = __builtin_amdgcn_mfma_f32_16x16x32_bf16(af[i],     qf[i],     Lc0, 0, 0, 0);
            Lc1 = __builtin_amdgcn_mfma_f32_16x16x32_bf16(af[i + 4], qf[i + 4], Lc1, 0, 0, 0);
        }

        bf16x4 e2;
#pragma unroll
        for (int r = 0; r < 4; ++r) {
            float E = __expf(fminf(Lc0[r] + Lc1[r], 30.f));
            lacc += E;
            e2[r] = f2bf(E);
        }

        __syncthreads();   // (A) previous tile's xT/Etmp reads complete

        // ---- scatter transpose into LDS (XOR-swizzled, proven) ----
#pragma unroll
        for (int i = 0; i < 8; ++i) {
            int Ki = (4 * i + q) & 7;
            int dbase = i * 32 + q * 8;
            bf16x8 f = af[i];
#pragma unroll
            for (int e = 0; e < 8; ++e) {
                int gp = (g0 ^ e ^ Ki) & 7;
                xT[((dbase + e) << 6) + (gp << 3) + t7] = f[e];
            }
        }
        *(bf16x4*)&Etmp[s16 * 72 + w * 16 + q * 4] = e2;

        __syncthreads();   // (B) xT + Etmp ready; af dead

        // ---- prefetch next tile's A-frags (pure global, overlaps U-GEMM) ----
        bf16x8 afn[8];
        if (!P1 && tt < 3) {
            const short* xr = xln + ((size_t)b * NTOK + tok + 64) * 256 + q * 8;
#pragma unroll
            for (int i = 0; i < 8; ++i) afn[i] = *(const bf16x8*)&xr[i * 32];
        }

        // ---- U-GEMM: gather from xT (proven conflict-free) ----
        bf16x8 ea0 = *(const bf16x8*)&Etmp[s16 * 72 + q * 8];
        bf16x8 ea1 = *(const bf16x8*)&Etmp[s16 * 72 + 32 + q * 8];
#pragma unroll
        for (int c = 0; c < 4; ++c) {
            int d = (4 * w + c) * 16 + s16;
            int swz = (d ^ (d >> 3)) & 7;
            const short* row = &xT[d << 6];
            bf16x8 b0 = *(const bf16x8*)&row[((q ^ swz) & 7) << 3];
            bf16x8 b1 = *(const bf16x8*)&row[(((4 + q) ^ swz) & 7) << 3];
            U[c] = __builtin_amdgcn_mfma_f32_16x16x32_bf16(ea0, b0, U[c], 0, 0, 0);
            U[c] = __builtin_amdgcn_mfma_f32_16x16x32_bf16(ea1, b1, U[c], 0, 0, 0);
        }

        if (!P1 && tt < 3) {
#pragma unroll
            for (int i = 0; i < 8; ++i) af[i] = afn[i];
        }
    }

    // ---- reduce l across quads/waves; store partials ----
    lacc += __shfl_xor(lacc, 16); lacc += __shfl_xor(lacc, 32);
    __syncthreads();
    if (q == 0 && s16 < 8) lsum[w][s16] = lacc;
    __syncthreads();
    float* lpart = ws + OFF_LPART + (size_t)(b * NPART + seg) * 16;
    if (t < 8) lpart[t] = lsum[0][t] + lsum[1][t] + lsum[2][t] + lsum[3][t];
    float* up = ws + OFF_UPART + (size_t)(b * NPART + seg) * NSLOT * 256;
#pragma unroll
    for (int c = 0; c < 4; ++c) {
        int d = (4 * w + c) * 16 + s16;
#pragma unroll
        for (int r = 0; r < 4; ++r) {
            int slot = q * 4 + r;
            if (slot < 8) up[slot * 256 + d] = U[c][r];
        }
    }
}

// ---------------- wave-per-row LN over 2 rows of [2][256] LDS ----------------
static __device__ __forceinline__ void ln_row2(const float* src, float* dst,
                                               const float* __restrict__ g,
                                               const float* __restrict__ be,
                                               int wave, int lane) {
    if (wave < 2) {
        float4 v = *(const float4*)(src + wave * 256 + lane * 4);
        float s1 = v.x + v.y + v.z + v.w;
        float s2 = v.x * v.x + v.y * v.y + v.z * v.z + v.w * v.w;
#pragma unroll
        for (int m = 1; m < 64; m <<= 1) { s1 += __shfl_xor(s1, m); s2 += __shfl_xor(s2, m); }
        float mu = s1 * (1.f / 256.f);
        float rstd = rsqrtf(s2 * (1.f / 256.f) - mu * mu + EPS);
        float4 gf = ((const float4*)g)[lane];
        float4 bf = ((const float4*)be)[lane];
        float4 o;
        o.x = (v.x - mu) * rstd * gf.x + bf.x;
        o.y = (v.y - mu) * rstd * gf.y + bf.y;
        o.z = (v.z - mu) * rstd * gf.z + bf.z;
        o.w = (v.w - mu) * rstd * gf.w + bf.w;
        *(float4*)(dst + wave * 256 + lane * 4) = o;
    }
}

// ---------------- fused slot pipeline (R3-proven): combine -> Wv -> GRU -> MLP -> (qt | out) ----------------
__global__ __launch_bounds__(512) void k_fused(float* __restrict__ ws,
                                               const float* __restrict__ b_ih,
                                               const float* __restrict__ b_hh,
                                               const float* __restrict__ g_ff,
                                               const float* __restrict__ be_ff,
                                               const float* __restrict__ b1p,
                                               const float* __restrict__ b2p,
                                               const float* __restrict__ g_sl,
                                               const float* __restrict__ be_sl,
                                               float* __restrict__ dout) {
    __shared__ __align__(16) float uc[2][256], upd[2][256], sl[2][256], snew[2][256];
    __shared__ __align__(16) float lnb[2][256], hbuf[2][256], so[2][256];
    __shared__ float lsv[2];

    int sp = blockIdx.x, b = blockIdx.y, t = threadIdx.x;
    int s0 = sp * 2;
    int s = t >> 8, d = t & 255;          // s wave-uniform
    int wave = t >> 6, lane = t & 63;

    // ---- Stage A: combine l partials for the 2 slots ----
    if (t < 32) {
        int ss = t >> 4, g = t & 15;
        float lv = ws[OFF_LPART + (size_t)(b * NPART + g) * 16 + s0 + ss];
#pragma unroll
        for (int m = 1; m < 16; m <<= 1) lv += __shfl_xor(lv, m);
        if ((t & 15) == 0) lsv[ss] = lv;
    }

    // ---- Stage B: combine U partials; load old slots ----
    const float* up0 = ws + OFF_UPART + (size_t)b * NPART * NSLOT * 256 + (s0 + s) * 256 + d;
    float acc = 0.f;
#pragma unroll
    for (int g = 0; g < NPART; ++g) acc += up0[(size_t)g * NSLOT * 256];
    sl[s][d] = ws[OFF_SLOTS + (size_t)b * 2048 + (s0 + s) * 256 + d];
    __syncthreads();
    uc[s][d] = acc / lsv[s];
    __syncthreads();

    // ---- Stage C: upd = uc @ WvT ----
    {
        const float* WvT = ws + OFF_WVT;
        float o = 0.f;
        for (int dd = 0; dd < 256; ++dd) o += uc[s][dd] * WvT[dd * 256 + d];
        upd[s][d] = o;
    }
    __syncthreads();

    // ---- Stage D: GRU cell ----
    {
        const float* WihT = ws + OFF_WIHT;
        const float* WhhT = ws + OFF_WHHT;
        float ar = 0.f, az = 0.f, an = 0.f, hr = 0.f, hz = 0.f, hn = 0.f;
        for (int dd = 0; dd < 256; ++dd) {
            float ud = upd[s][dd], sd = sl[s][dd];
            const float* wi = WihT + dd * 768;
            const float* wh = WhhT + dd * 768;
            ar += ud * wi[d];       az += ud * wi[256 + d]; an += ud * wi[512 + d];
            hr += sd * wh[d];       hz += sd * wh[256 + d]; hn += sd * wh[512 + d];
        }
        float rg = 1.f / (1.f + __expf(-(ar + b_ih[d] + hr + b_hh[d])));
        float zg = 1.f / (1.f + __expf(-(az + b_ih[256 + d] + hz + b_hh[256 + d])));
        float ng = tanhf(an + b_ih[512 + d] + rg * (hn + b_hh[512 + d]));
        snew[s][d] = (1.f - zg) * ng + zg * sl[s][d];
    }
    __syncthreads();

    // ---- Stage E: LN(snew, g_ff, be_ff) ----
    ln_row2(&snew[0][0], &lnb[0][0], g_ff, be_ff, wave, lane);
    __syncthreads();

    // ---- Stage F: h = relu(lnb @ W1T + b1) ----
    {
        const float* W1T = ws + OFF_W1T;
        float o = 0.f;
        for (int dd = 0; dd < 256; ++dd) o += lnb[s][dd] * W1T[dd * 256 + d];
        hbuf[s][d] = fmaxf(o + b1p[d], 0.f);
    }
    __syncthreads();

    // ---- Stage G: slots_out = snew + h @ W2T + b2 ----
    {
        const float* W2T = ws + OFF_W2T;
        float o = 0.f;
        for (int dd = 0; dd < 256; ++dd) o += hbuf[s][dd] * W2T[dd * 256 + d];
        float r = snew[s][d] + o + b2p[d];
        so[s][d] = r;
        ws[OFF_SLOTS + (size_t)b * 2048 + (s0 + s) * 256 + d] = r;
        if (dout) dout[(size_t)b * 2048 + (s0 + s) * 256 + d] = r;
    }

    // ---- Stage H (non-final iters): qt = LN(slots_out, g_sl) @ M ----
    if (!dout) {
        __syncthreads();
        ln_row2(&so[0][0], &lnb[0][0], g_sl, be_sl, wave, lane);
        __syncthreads();
        const float* M = ws + OFF_M;
        float o = 0.f;
        for (int dd = 0; dd < 256; ++dd) o += lnb[s][dd] * M[dd * 256 + d];
        ws[OFF_QT + (size_t)b * 2048 + (s0 + s) * 256 + d] = o;
    }
}

extern "C" void kernel_launch(void* const* d_in, const int* in_sizes, int n_in,
                              void* d_out, int out_size, void* d_ws, size_t ws_size,
                              hipStream_t stream) {
    const float* x      = (const float*)d_in[0];
    const float* noise  = (const float*)d_in[1];
    const float* mu     = (const float*)d_in[2];
    const float* logsig = (const float*)d_in[3];
    const float* Wq     = (const float*)d_in[4];
    const float* Wk     = (const float*)d_in[5];
    const float* Wv     = (const float*)d_in[6];
    const float* W_ih   = (const float*)d_in[7];
    const float* W_hh   = (const float*)d_in[8];
    const float* b_ih   = (const float*)d_in[9];
    const float* b_hh   = (const float*)d_in[10];
    const float* W1     = (const float*)d_in[11];
    const float* b1     = (const float*)d_in[12];
    const float* W2     = (const float*)d_in[13];
    const float* b2     = (const float*)d_in[14];
    const float* g_in   = (const float*)d_in[15];
    const float* be_in  = (const float*)d_in[16];
    const float* g_sl   = (const float*)d_in[17];
    const float* be_sl  = (const float*)d_in[18];
    const float* g_ff   = (const float*)d_in[19];
    const float* be_ff  = (const float*)d_in[20];
    float* ws = (float*)d_ws;
    float* out = (float*)d_out;

    hipLaunchKernelGGL(k_pre, dim3(1344), dim3(256), 0, stream,
                       W_ih, W_hh, Wv, W1, W2, Wq, Wk, mu, logsig, noise, ws);
    hipLaunchKernelGGL(k_qt, dim3(4, 64), dim3(256), 0, stream, ws, g_sl, be_sl);
    for (int it = 0; it < ITERS; ++it) {
        if (it == 0)
            hipLaunchKernelGGL((k_attn_t<true>),  dim3(SEGB, 64), dim3(256), 0, stream, x, g_in, be_in, ws);
        else
            hipLaunchKernelGGL((k_attn_t<false>), dim3(SEGB, 64), dim3(256), 0, stream, x, g_in, be_in, ws);
        hipLaunchKernelGGL(k_fused, dim3(4, 64), dim3(512), 0, stream, ws,
                           b_ih, b_hh, g_ff, be_ff, b1, b2, g_sl, be_sl,
                           (it == ITERS - 1) ? out : nullptr);
    }
}